// Round 3
// baseline (292.276 us; speedup 1.0000x reference)
//
#include <hip/hip_runtime.h>

typedef __attribute__((ext_vector_type(8))) short bf16x8;
typedef __attribute__((ext_vector_type(4))) float f32x4;

#define HH 768
#define EE 768
#define BB 32
#define SS 512
#define PP 76
#define KCAND 64
#define MM (BB * PP)     // 2432
#define VV 50257

// ws byte offsets (16B aligned)
#define OFF_WT    0u          // bf16 768*768   = 1,179,648
#define OFF_AG    1179648u    // bf16 2432*768  = 3,735,552
#define OFF_LM    4915200u    // fp32 2432*768  = 7,471,104

#define WT_BLOCKS 576
#define AG_BLOCKS 304
#define GEMM_BLOCKS 456      // 12 x 38

__device__ inline unsigned short f2bf(float f) {
    unsigned int u = __float_as_uint(f);
    u += 0x7fffu + ((u >> 16) & 1u);
    return (unsigned short)(u >> 16);
}
__device__ inline float bf2f(unsigned short h) {
    return __uint_as_float(((unsigned int)h) << 16);
}

// L1: W transpose+convert -> Wt[e][h] ; gather masked rows -> Ag[m][k].
__global__ __launch_bounds__(256) void prep_kernel(
    const float* __restrict__ W, unsigned short* __restrict__ Wt,
    const float* __restrict__ seq, const int* __restrict__ mpos,
    unsigned short* __restrict__ Ag) {
    const int bid = blockIdx.x;
    if (bid < WT_BLOCKS) {
        __shared__ float tile[32][33];
        const int h0 = (bid % 24) * 32, e0 = (bid / 24) * 32;
        const int c = threadIdx.x & 31, r = threadIdx.x >> 5;
#pragma unroll
        for (int rr = r; rr < 32; rr += 8)
            tile[rr][c] = W[(size_t)(h0 + rr) * EE + e0 + c];
        __syncthreads();
#pragma unroll
        for (int rr = r; rr < 32; rr += 8)
            Wt[(size_t)(e0 + rr) * HH + h0 + c] = f2bf(tile[c][rr]);
    } else {
        const int m0 = (bid - WT_BLOCKS) * 8;
        const int t = threadIdx.x;
#pragma unroll
        for (int rr = 0; rr < 8; ++rr) {
            const int m = m0 + rr;
            const int b = m / PP, p = m - b * PP;
            const int ps = mpos[b * PP + p];
            const float* srow = seq + (size_t)(b * SS + ps) * HH;
            unsigned short* drow = Ag + (size_t)m * HH;
#pragma unroll
            for (int j = 0; j < 3; ++j)
                drow[t + j * 256] = f2bf(srow[t + j * 256]);
        }
    }
}

// L2: bf16 MFMA GEMM (64x64 tile, BK=64) -> lm fp32.
__global__ __launch_bounds__(256) void gemm_kernel(
    const unsigned short* __restrict__ Ag, const unsigned short* __restrict__ Wt,
    float* __restrict__ lm) {
    __shared__ unsigned short Alds[64][72];
    __shared__ unsigned short Blds[64][72];
    const int bid = blockIdx.x;
    const int bn = bid % 12, bm = bid / 12;
    const int tid = threadIdx.x;
    const int sr = tid >> 2, sc = (tid & 3) * 16;
    const unsigned short* abase = Ag + (size_t)(bm * 64) * HH;
    const unsigned short* bbase = Wt + (size_t)(bn * 64) * HH;
    const int lane = tid & 63, wv = tid >> 6;
    const int wm = wv >> 1, wn = wv & 1;
    const int fr = lane & 15, fq = (lane >> 4) * 8;
    f32x4 acc[2][2] = {};
    for (int kk = 0; kk < HH; kk += 64) {
        __syncthreads();
        *(int4*)&Alds[sr][sc]     = *(const int4*)(abase + (size_t)sr * HH + kk + sc);
        *(int4*)&Alds[sr][sc + 8] = *(const int4*)(abase + (size_t)sr * HH + kk + sc + 8);
        *(int4*)&Blds[sr][sc]     = *(const int4*)(bbase + (size_t)sr * HH + kk + sc);
        *(int4*)&Blds[sr][sc + 8] = *(const int4*)(bbase + (size_t)sr * HH + kk + sc + 8);
        __syncthreads();
#pragma unroll
        for (int ks = 0; ks < 64; ks += 32) {
            bf16x8 af[2], bfr[2];
#pragma unroll
            for (int t = 0; t < 2; ++t)
                af[t] = *(const bf16x8*)&Alds[wm * 32 + t * 16 + fr][ks + fq];
#pragma unroll
            for (int t = 0; t < 2; ++t)
                bfr[t] = *(const bf16x8*)&Blds[wn * 32 + t * 16 + fr][ks + fq];
#pragma unroll
            for (int tm = 0; tm < 2; ++tm)
#pragma unroll
                for (int tn = 0; tn < 2; ++tn)
                    acc[tm][tn] = __builtin_amdgcn_mfma_f32_16x16x32_bf16(
                        af[tm], bfr[tn], acc[tm][tn], 0, 0, 0);
        }
    }
#pragma unroll
    for (int tm = 0; tm < 2; ++tm)
#pragma unroll
        for (int tn = 0; tn < 2; ++tn) {
            const int col = bn * 64 + wn * 32 + tn * 16 + (lane & 15);
            const int rbase = bm * 64 + wm * 32 + tm * 16 + (lane >> 4) * 4;
#pragma unroll
            for (int g = 0; g < 4; ++g)
                lm[(size_t)(rbase + g) * EE + col] = acc[tm][tn][g];
        }
}

// L3: one block per output row m.
//  Phase A: bias + LayerNorm of lm[m] -> bf16 in LDS (block-local, no lmn buffer,
//           no cross-kernel round-trip).
//  Phase B: 16 groups of 16 lanes; each group handles 4 of the row's 64
//           candidates (2-wide ILP). emb rows streamed with perfectly coalesced
//           256B-per-instruction group reads; LDS reads broadcast across groups.
//  No dedup machinery: no atomics, no cursor, no perm2, no overflow path.
__global__ __launch_bounds__(256) void mrow_logits_kernel(
    const float* __restrict__ lm, const float* __restrict__ bias,
    const float* __restrict__ gamma, const float* __restrict__ beta,
    const int* __restrict__ cand, const float* __restrict__ emb,
    float* __restrict__ out) {
    const int m = blockIdx.x;
    const int t = threadIdx.x;
    __shared__ unsigned short lmn_s[EE];
    __shared__ float redS[4], redQ[4];

    // ---- Phase A: LayerNorm(lm[m] + bias) ----
    const float x0 = lm[(size_t)m * EE + t]       + bias[t];
    const float x1 = lm[(size_t)m * EE + t + 256] + bias[t + 256];
    const float x2 = lm[(size_t)m * EE + t + 512] + bias[t + 512];
    float s = x0 + x1 + x2;
    float q = x0 * x0 + x1 * x1 + x2 * x2;
#pragma unroll
    for (int w = 32; w; w >>= 1) { s += __shfl_xor(s, w); q += __shfl_xor(q, w); }
    const int lane = t & 63, wv = t >> 6;
    if (lane == 0) { redS[wv] = s; redQ[wv] = q; }
    __syncthreads();
    s = redS[0] + redS[1] + redS[2] + redS[3];
    q = redQ[0] + redQ[1] + redQ[2] + redQ[3];
    const float mu = s * (1.0f / 768.0f);
    const float rstd = rsqrtf(q * (1.0f / 768.0f) - mu * mu + 1e-12f);
    lmn_s[t]       = f2bf((x0 - mu) * rstd * gamma[t]       + beta[t]);
    lmn_s[t + 256] = f2bf((x1 - mu) * rstd * gamma[t + 256] + beta[t + 256]);
    lmn_s[t + 512] = f2bf((x2 - mu) * rstd * gamma[t + 512] + beta[t + 512]);
    __syncthreads();

    // ---- Phase B: 64 candidate dots ----
    const int g = t >> 4, l16 = t & 15;
    // lane's 48 normalized elements: {4*l16 + 64*j + 0..3}, j = 0..11
    ushort4 ln4[12];
#pragma unroll
    for (int j = 0; j < 12; ++j)
        ln4[j] = *(const ushort4*)&lmn_s[4 * l16 + 64 * j];

    const f32x4* e4 = (const f32x4*)emb;
    const int cb = m * 64 + g;
#pragma unroll
    for (int kk = 0; kk < 4; kk += 2) {
        const int r0 = cand[cb + 16 * kk];
        const int r1 = cand[cb + 16 * kk + 16];
        const f32x4* p0 = e4 + (size_t)r0 * 192 + l16;
        const f32x4* p1 = e4 + (size_t)r1 * 192 + l16;
        f32x4 A0[12], A1[12];
#pragma unroll
        for (int j = 0; j < 12; ++j) { A0[j] = p0[16 * j]; A1[j] = p1[16 * j]; }
        float d0 = 0.f, d1 = 0.f;
#pragma unroll
        for (int j = 0; j < 12; ++j) {
            d0 += bf2f(ln4[j].x) * A0[j][0] + bf2f(ln4[j].y) * A0[j][1]
                + bf2f(ln4[j].z) * A0[j][2] + bf2f(ln4[j].w) * A0[j][3];
            d1 += bf2f(ln4[j].x) * A1[j][0] + bf2f(ln4[j].y) * A1[j][1]
                + bf2f(ln4[j].z) * A1[j][2] + bf2f(ln4[j].w) * A1[j][3];
        }
#pragma unroll
        for (int w = 1; w < 16; w <<= 1) { d0 += __shfl_xor(d0, w); d1 += __shfl_xor(d1, w); }
        if (l16 == 0) {
            out[cb + 16 * kk] = d0;
            out[cb + 16 * kk + 16] = d1;
        }
    }
}

extern "C" void kernel_launch(void* const* d_in, const int* in_sizes, int n_in,
                              void* d_out, int out_size, void* d_ws, size_t ws_size,
                              hipStream_t stream) {
    const float* seq   = (const float*)d_in[0];
    const int*   mpos  = (const int*)d_in[1];
    const int*   cand  = (const int*)d_in[2];
    const float* emb   = (const float*)d_in[3];
    const float* W     = (const float*)d_in[4];
    const float* bias  = (const float*)d_in[5];
    const float* gamma = (const float*)d_in[6];
    const float* beta  = (const float*)d_in[7];
    float* out = (float*)d_out;

    char* ws = (char*)d_ws;
    unsigned short* Wt = (unsigned short*)(ws + OFF_WT);
    unsigned short* Ag = (unsigned short*)(ws + OFF_AG);
    float*          lm = (float*)(ws + OFF_LM);

    prep_kernel<<<WT_BLOCKS + AG_BLOCKS, 256, 0, stream>>>(W, Wt, seq, mpos, Ag);
    gemm_kernel<<<GEMM_BLOCKS, 256, 0, stream>>>(Ag, Wt, lm);
    mrow_logits_kernel<<<MM, 256, 0, stream>>>(lm, bias, gamma, beta, cand, emb, out);
}

// Round 4
// 291.992 us; speedup vs baseline: 1.0010x; 1.0010x over previous
//
#include <hip/hip_runtime.h>

typedef __attribute__((ext_vector_type(8))) short bf16x8;
typedef __attribute__((ext_vector_type(4))) float f32x4;

#define HH 768
#define EE 768
#define BB 32
#define SS 512
#define PP 76
#define KCAND 64
#define MM (BB * PP)     // 2432
#define VV 50257

// ws byte offsets (16B aligned)
#define OFF_WT    0u          // bf16 768*768   = 1,179,648
#define OFF_AG    1179648u    // bf16 2432*768  = 3,735,552
#define OFF_LM    4915200u    // fp32 2432*768  = 7,471,104

#define WT_BLOCKS 576
#define AG_BLOCKS 304
#define GEMM_BLOCKS 456      // 12 x 38

__device__ inline unsigned short f2bf(float f) {
    unsigned int u = __float_as_uint(f);
    u += 0x7fffu + ((u >> 16) & 1u);
    return (unsigned short)(u >> 16);
}
__device__ inline float bf2f(unsigned short h) {
    return __uint_as_float(((unsigned int)h) << 16);
}

// L1: W transpose+convert -> Wt[e][h] ; gather masked rows -> Ag[m][k].
__global__ __launch_bounds__(256) void prep_kernel(
    const float* __restrict__ W, unsigned short* __restrict__ Wt,
    const float* __restrict__ seq, const int* __restrict__ mpos,
    unsigned short* __restrict__ Ag) {
    const int bid = blockIdx.x;
    if (bid < WT_BLOCKS) {
        __shared__ float tile[32][33];
        const int h0 = (bid % 24) * 32, e0 = (bid / 24) * 32;
        const int c = threadIdx.x & 31, r = threadIdx.x >> 5;
#pragma unroll
        for (int rr = r; rr < 32; rr += 8)
            tile[rr][c] = W[(size_t)(h0 + rr) * EE + e0 + c];
        __syncthreads();
#pragma unroll
        for (int rr = r; rr < 32; rr += 8)
            Wt[(size_t)(e0 + rr) * HH + h0 + c] = f2bf(tile[c][rr]);
    } else {
        const int m0 = (bid - WT_BLOCKS) * 8;
        const int t = threadIdx.x;
#pragma unroll
        for (int rr = 0; rr < 8; ++rr) {
            const int m = m0 + rr;
            const int b = m / PP, p = m - b * PP;
            const int ps = mpos[b * PP + p];
            const float* srow = seq + (size_t)(b * SS + ps) * HH;
            unsigned short* drow = Ag + (size_t)m * HH;
#pragma unroll
            for (int j = 0; j < 3; ++j)
                drow[t + j * 256] = f2bf(srow[t + j * 256]);
        }
    }
}

// L2: bf16 MFMA GEMM (64x64 tile, BK=64) -> lm fp32.
__global__ __launch_bounds__(256) void gemm_kernel(
    const unsigned short* __restrict__ Ag, const unsigned short* __restrict__ Wt,
    float* __restrict__ lm) {
    __shared__ unsigned short Alds[64][72];
    __shared__ unsigned short Blds[64][72];
    const int bid = blockIdx.x;
    const int bn = bid % 12, bm = bid / 12;
    const int tid = threadIdx.x;
    const int sr = tid >> 2, sc = (tid & 3) * 16;
    const unsigned short* abase = Ag + (size_t)(bm * 64) * HH;
    const unsigned short* bbase = Wt + (size_t)(bn * 64) * HH;
    const int lane = tid & 63, wv = tid >> 6;
    const int wm = wv >> 1, wn = wv & 1;
    const int fr = lane & 15, fq = (lane >> 4) * 8;
    f32x4 acc[2][2] = {};
    for (int kk = 0; kk < HH; kk += 64) {
        __syncthreads();
        *(int4*)&Alds[sr][sc]     = *(const int4*)(abase + (size_t)sr * HH + kk + sc);
        *(int4*)&Alds[sr][sc + 8] = *(const int4*)(abase + (size_t)sr * HH + kk + sc + 8);
        *(int4*)&Blds[sr][sc]     = *(const int4*)(bbase + (size_t)sr * HH + kk + sc);
        *(int4*)&Blds[sr][sc + 8] = *(const int4*)(bbase + (size_t)sr * HH + kk + sc + 8);
        __syncthreads();
#pragma unroll
        for (int ks = 0; ks < 64; ks += 32) {
            bf16x8 af[2], bfr[2];
#pragma unroll
            for (int t = 0; t < 2; ++t)
                af[t] = *(const bf16x8*)&Alds[wm * 32 + t * 16 + fr][ks + fq];
#pragma unroll
            for (int t = 0; t < 2; ++t)
                bfr[t] = *(const bf16x8*)&Blds[wn * 32 + t * 16 + fr][ks + fq];
#pragma unroll
            for (int tm = 0; tm < 2; ++tm)
#pragma unroll
                for (int tn = 0; tn < 2; ++tn)
                    acc[tm][tn] = __builtin_amdgcn_mfma_f32_16x16x32_bf16(
                        af[tm], bfr[tn], acc[tm][tn], 0, 0, 0);
        }
    }
#pragma unroll
    for (int tm = 0; tm < 2; ++tm)
#pragma unroll
        for (int tn = 0; tn < 2; ++tn) {
            const int col = bn * 64 + wn * 32 + tn * 16 + (lane & 15);
            const int rbase = bm * 64 + wm * 32 + tm * 16 + (lane >> 4) * 4;
#pragma unroll
            for (int g = 0; g < 4; ++g)
                lm[(size_t)(rbase + g) * EE + col] = acc[tm][tn][g];
        }
}

// L3: one block per output row m.
//  Phase A: cand indices -> LDS; bias + LayerNorm of lm[m] -> bf16 in LDS.
//  Phase B: 16 groups x 16 lanes; each group does its 4 candidates 4-WIDE:
//           all 48 f32x4 emb loads issued before any FMA (sched_barrier pins
//           the schedule) -> ~48 outstanding loads/wave to hide HBM latency.
__global__ __launch_bounds__(256, 2) void mrow_logits_kernel(
    const float* __restrict__ lm, const float* __restrict__ bias,
    const float* __restrict__ gamma, const float* __restrict__ beta,
    const int* __restrict__ cand, const float* __restrict__ emb,
    float* __restrict__ out) {
    const int m = blockIdx.x;
    const int t = threadIdx.x;
    __shared__ unsigned short lmn_s[EE];
    __shared__ float redS[4], redQ[4];
    __shared__ int cand_s[KCAND];

    if (t < KCAND) cand_s[t] = cand[m * KCAND + t];

    // ---- Phase A: LayerNorm(lm[m] + bias) ----
    const float x0 = lm[(size_t)m * EE + t]       + bias[t];
    const float x1 = lm[(size_t)m * EE + t + 256] + bias[t + 256];
    const float x2 = lm[(size_t)m * EE + t + 512] + bias[t + 512];
    float s = x0 + x1 + x2;
    float q = x0 * x0 + x1 * x1 + x2 * x2;
#pragma unroll
    for (int w = 32; w; w >>= 1) { s += __shfl_xor(s, w); q += __shfl_xor(q, w); }
    const int lane = t & 63, wv = t >> 6;
    if (lane == 0) { redS[wv] = s; redQ[wv] = q; }
    __syncthreads();
    s = redS[0] + redS[1] + redS[2] + redS[3];
    q = redQ[0] + redQ[1] + redQ[2] + redQ[3];
    const float mu = s * (1.0f / 768.0f);
    const float rstd = rsqrtf(q * (1.0f / 768.0f) - mu * mu + 1e-12f);
    lmn_s[t]       = f2bf((x0 - mu) * rstd * gamma[t]       + beta[t]);
    lmn_s[t + 256] = f2bf((x1 - mu) * rstd * gamma[t + 256] + beta[t + 256]);
    lmn_s[t + 512] = f2bf((x2 - mu) * rstd * gamma[t + 512] + beta[t + 512]);
    __syncthreads();

    // ---- Phase B: 64 candidate dots, 4-wide per 16-lane group ----
    const int g = t >> 4, l16 = t & 15;
    ushort4 ln4[12];
#pragma unroll
    for (int j = 0; j < 12; ++j)
        ln4[j] = *(const ushort4*)&lmn_s[4 * l16 + 64 * j];

    const f32x4* e4 = (const f32x4*)emb;
    const int cb = m * KCAND + g;
    const f32x4* p0 = e4 + (size_t)cand_s[g]      * 192 + l16;
    const f32x4* p1 = e4 + (size_t)cand_s[g + 16] * 192 + l16;
    const f32x4* p2 = e4 + (size_t)cand_s[g + 32] * 192 + l16;
    const f32x4* p3 = e4 + (size_t)cand_s[g + 48] * 192 + l16;
    f32x4 A0[12], A1[12], A2[12], A3[12];
#pragma unroll
    for (int j = 0; j < 12; ++j) A0[j] = p0[16 * j];
#pragma unroll
    for (int j = 0; j < 12; ++j) A1[j] = p1[16 * j];
#pragma unroll
    for (int j = 0; j < 12; ++j) A2[j] = p2[16 * j];
#pragma unroll
    for (int j = 0; j < 12; ++j) A3[j] = p3[16 * j];
    __builtin_amdgcn_sched_barrier(0);   // all 48 loads issued before any FMA

    float d0 = 0.f, d1 = 0.f, d2 = 0.f, d3 = 0.f;
    float f0 = 0.f, f1 = 0.f, f2 = 0.f, f3 = 0.f;
#pragma unroll
    for (int j = 0; j < 12; j += 2) {
        float la[4], lb[4];
        la[0] = bf2f(ln4[j].x);     la[1] = bf2f(ln4[j].y);
        la[2] = bf2f(ln4[j].z);     la[3] = bf2f(ln4[j].w);
        lb[0] = bf2f(ln4[j + 1].x); lb[1] = bf2f(ln4[j + 1].y);
        lb[2] = bf2f(ln4[j + 1].z); lb[3] = bf2f(ln4[j + 1].w);
        d0 += la[0]*A0[j][0] + la[1]*A0[j][1] + la[2]*A0[j][2] + la[3]*A0[j][3];
        d1 += la[0]*A1[j][0] + la[1]*A1[j][1] + la[2]*A1[j][2] + la[3]*A1[j][3];
        d2 += la[0]*A2[j][0] + la[1]*A2[j][1] + la[2]*A2[j][2] + la[3]*A2[j][3];
        d3 += la[0]*A3[j][0] + la[1]*A3[j][1] + la[2]*A3[j][2] + la[3]*A3[j][3];
        f0 += lb[0]*A0[j+1][0] + lb[1]*A0[j+1][1] + lb[2]*A0[j+1][2] + lb[3]*A0[j+1][3];
        f1 += lb[0]*A1[j+1][0] + lb[1]*A1[j+1][1] + lb[2]*A1[j+1][2] + lb[3]*A1[j+1][3];
        f2 += lb[0]*A2[j+1][0] + lb[1]*A2[j+1][1] + lb[2]*A2[j+1][2] + lb[3]*A2[j+1][3];
        f3 += lb[0]*A3[j+1][0] + lb[1]*A3[j+1][1] + lb[2]*A3[j+1][2] + lb[3]*A3[j+1][3];
    }
    d0 += f0; d1 += f1; d2 += f2; d3 += f3;
#pragma unroll
    for (int w = 1; w < 16; w <<= 1) {
        d0 += __shfl_xor(d0, w); d1 += __shfl_xor(d1, w);
        d2 += __shfl_xor(d2, w); d3 += __shfl_xor(d3, w);
    }
    if (l16 == 0) {
        out[cb]      = d0;
        out[cb + 16] = d1;
        out[cb + 32] = d2;
        out[cb + 48] = d3;
    }
}

extern "C" void kernel_launch(void* const* d_in, const int* in_sizes, int n_in,
                              void* d_out, int out_size, void* d_ws, size_t ws_size,
                              hipStream_t stream) {
    const float* seq   = (const float*)d_in[0];
    const int*   mpos  = (const int*)d_in[1];
    const int*   cand  = (const int*)d_in[2];
    const float* emb   = (const float*)d_in[3];
    const float* W     = (const float*)d_in[4];
    const float* bias  = (const float*)d_in[5];
    const float* gamma = (const float*)d_in[6];
    const float* beta  = (const float*)d_in[7];
    float* out = (float*)d_out;

    char* ws = (char*)d_ws;
    unsigned short* Wt = (unsigned short*)(ws + OFF_WT);
    unsigned short* Ag = (unsigned short*)(ws + OFF_AG);
    float*          lm = (float*)(ws + OFF_LM);

    prep_kernel<<<WT_BLOCKS + AG_BLOCKS, 256, 0, stream>>>(W, Wt, seq, mpos, Ag);
    gemm_kernel<<<GEMM_BLOCKS, 256, 0, stream>>>(Ag, Wt, lm);
    mrow_logits_kernel<<<MM, 256, 0, stream>>>(lm, bias, gamma, beta, cand, emb, out);
}